// Round 1
// baseline (1834.909 us; speedup 1.0000x reference)
//
#include <hip/hip_runtime.h>
#include <hip/hip_bf16.h>

#define N_NODE  100000
#define N_EDGE  800000
#define FEATD   128

typedef float  f32x4 __attribute__((ext_vector_type(4)));
typedef short  s16x8 __attribute__((ext_vector_type(8)));
typedef short  s16x4 __attribute__((ext_vector_type(4)));

static __device__ __forceinline__ float bf2f(ushort h) {
    union { uint u; float f; } v; v.u = ((uint)h) << 16; return v.f;
}
static __device__ __forceinline__ ushort f2bf(float f) {
    union { float f; uint u; } v; v.f = f;
    uint u = v.u;
    u = u + 0x7FFFu + ((u >> 16) & 1u);   // RNE
    return (ushort)(u >> 16);
}

// ---------------- K1: weights f32 -> bf16 (packed into ws) ----------------
// Layout in Wbf (shorts): Wl[16384] Wr[16384] W1[8192] W2[2048]  (total 43008)
__global__ void k_convert_weights(const float* __restrict__ Wl, const float* __restrict__ Wr,
                                  const float* __restrict__ W1, const float* __restrict__ W2,
                                  ushort* __restrict__ Wbf) {
    int i = blockIdx.x * 256 + threadIdx.x;
    if (i < 16384)       Wbf[i] = f2bf(Wl[i]);
    else if (i < 32768)  Wbf[i] = f2bf(Wr[i - 16384]);
    else if (i < 40960)  Wbf[i] = f2bf(W1[i - 32768]);
    else if (i < 43008)  Wbf[i] = f2bf(W2[i - 40960]);
}

// ---------------- K2: n_fea (concat rna|prot) f32 -> bf16 ----------------
__global__ void k_convert_nfea(const float* __restrict__ rna, const float* __restrict__ prot,
                               ushort* __restrict__ nfbf) {
    int i = (blockIdx.x * 256 + threadIdx.x) * 4;
    if (i >= N_NODE * FEATD) return;
    const float* src = (i < 50000 * FEATD) ? (rna + i) : (prot + (i - 50000 * FEATD));
    float4 v = *(const float4*)src;
    ushort4 o;
    o.x = f2bf(v.x); o.y = f2bf(v.y); o.z = f2bf(v.z); o.w = f2bf(v.w);
    *(ushort4*)(nfbf + i) = o;
}

// ---------------- K3: scatter  agg[dst[e]] += x[src[e]],  cnt[dst[e]] += 1 ----
// x[s] = n_fea[src[s]] * n_fea[dst[s]]  (double indirection; s < 100000 always)
__global__ void k_scatter(const int* __restrict__ ei, const ushort* __restrict__ nfbf,
                          float* __restrict__ agg, float* __restrict__ cnt) {
    int t   = blockIdx.x * 256 + threadIdx.x;
    int e   = t >> 5;         // 32 lanes per edge
    int sub = t & 31;
    int s  = ei[e];
    int d  = ei[N_EDGE + e];
    int s2 = ei[s];
    int d2 = ei[N_EDGE + s];
    s16x4 a = *(const s16x4*)(nfbf + s2 * FEATD + sub * 4);
    s16x4 b = *(const s16x4*)(nfbf + d2 * FEATD + sub * 4);
    float* dst = agg + (size_t)d * FEATD + sub * 4;
#pragma unroll
    for (int j = 0; j < 4; ++j) {
        float v = bf2f((ushort)a[j]) * bf2f((ushort)b[j]);
        unsafeAtomicAdd(dst + j, v);
    }
    if (sub == 0) unsafeAtomicAdd(cnt + d, 1.0f);
}

// ---------------- K5: labels ----------------
__global__ void k_labels(float* __restrict__ out) {
    int base = (blockIdx.x * 256 + threadIdx.x) * 4;
    if (base >= N_EDGE) return;
    float val = (base < N_EDGE / 2) ? 1.0f : 0.0f;   // 400000 % 4 == 0: no straddle
    float4 v = { val, val, val, val };
    *(float4*)(out + 2 * (size_t)N_EDGE + base) = v;
}

// ---------------- K4: fused gather + 4-layer MLP + log_softmax ----------------
// LDS layout (bytes), all weight/buf rows XOR-swizzled: byte ^= (row&7)<<4
#define LOFF_WL   0
#define LOFF_WR   32768
#define LOFF_W1   65536
#define LOFF_W2   81920      /* 32 rows x 128B */
#define LOFF_BL   86016
#define LOFF_B1   86528
#define LOFF_B2   86784
#define LOFF_W3   86912      /* 64 f32: W3[2][32] */
#define LOFF_B3   87168
#define LOFF_XBUF 87184      /* 8 waves x 4096B: [16 rows][256B] */
#define LOFF_MBUF (87184 + 8 * 4096)
#define LDS_TOTAL (LOFF_MBUF + 8 * 4096)   /* 152720 */

__global__ __launch_bounds__(512) void k_mlp(
        const int* __restrict__ ei, const ushort* __restrict__ nfbf,
        const float* __restrict__ agg, const float* __restrict__ cnt,
        const ushort* __restrict__ Wbf,
        const float* __restrict__ bl, const float* __restrict__ b1,
        const float* __restrict__ b2, const float* __restrict__ W3,
        const float* __restrict__ b3, float* __restrict__ out)
{
    extern __shared__ char smem[];
    const int tid = threadIdx.x;

    // ---- stage weights (cooperative) ----
    {
        const uint4* src = (const uint4*)Wbf;   // 16B chunks: Wl 2048 | Wr 2048 | W1 1024 | W2 256
        for (int c = tid; c < 2048; c += 512) {
            int row = c >> 4, colb = (c & 15) << 4;
            *(uint4*)(smem + LOFF_WL + row * 256 + (colb ^ ((row & 7) << 4))) = src[c];
        }
        for (int c = tid; c < 2048; c += 512) {
            int row = c >> 4, colb = (c & 15) << 4;
            *(uint4*)(smem + LOFF_WR + row * 256 + (colb ^ ((row & 7) << 4))) = src[2048 + c];
        }
        for (int c = tid; c < 1024; c += 512) {
            int row = c >> 4, colb = (c & 15) << 4;
            *(uint4*)(smem + LOFF_W1 + row * 256 + (colb ^ ((row & 7) << 4))) = src[4096 + c];
        }
        for (int c = tid; c < 256; c += 512) {
            int row = c >> 3, colb = (c & 7) << 4;
            *(uint4*)(smem + LOFF_W2 + row * 128 + (colb ^ ((row & 7) << 4))) = src[5120 + c];
        }
        if (tid < 128)      *(float*)(smem + LOFF_BL + tid * 4) = bl[tid];
        else if (tid < 192) *(float*)(smem + LOFF_B1 + (tid - 128) * 4) = b1[tid - 128];
        else if (tid < 224) *(float*)(smem + LOFF_B2 + (tid - 192) * 4) = b2[tid - 192];
        else if (tid < 288) *(float*)(smem + LOFF_W3 + (tid - 224) * 4) = W3[tid - 224];
        else if (tid < 290) *(float*)(smem + LOFF_B3 + (tid - 288) * 4) = b3[tid - 288];
    }
    __syncthreads();

    const int w = tid >> 6, lane = tid & 63;
    const int eb = blockIdx.x * 128 + w * 16;
    char* xb = smem + LOFF_XBUF + w * 4096;
    char* mb = smem + LOFF_MBUF + w * 4096;
    const bool has_mean = (eb < N_NODE);   // tiles are 16-aligned; 100000 % 16 == 0

    // ---- gather: x rows (bf16) and mean rows into LDS ----
#pragma unroll
    for (int i = 0; i < 16; ++i) {
        int e = eb + i;
        int s = ei[e], d = ei[N_EDGE + e];
        uint ua = *(const uint*)(nfbf + (size_t)s * FEATD + lane * 2);
        uint ub = *(const uint*)(nfbf + (size_t)d * FEATD + lane * 2);
        float p0 = bf2f((ushort)(ua & 0xFFFF)) * bf2f((ushort)(ub & 0xFFFF));
        float p1 = bf2f((ushort)(ua >> 16))    * bf2f((ushort)(ub >> 16));
        uint pk = (uint)f2bf(p0) | ((uint)f2bf(p1) << 16);
        *(uint*)(xb + i * 256 + ((lane * 4) ^ ((i & 7) << 4))) = pk;
        if (has_mean) {
            float sc = 1.0f / fmaxf(cnt[e], 1.0f);
            float2 m2 = *(const float2*)(agg + (size_t)e * FEATD + lane * 2);
            uint mk = (uint)f2bf(m2.x * sc) | ((uint)f2bf(m2.y * sc) << 16);
            *(uint*)(mb + i * 256 + ((lane * 4) ^ ((i & 7) << 4))) = mk;
        }
    }

    const int arow = lane & 15, agrp = lane >> 4;
    const int acol = agrp * 16;   // byte offset of this lane's 16B chunk within a 64B k-step

    // ---- A fragments for layer 1 ----
    s16x8 ax[4], am[4] = {};
#pragma unroll
    for (int t = 0; t < 4; ++t) {
        int off = arow * 256 + (((t * 64) + acol) ^ ((arow & 7) << 4));
        ax[t] = *(const s16x8*)(xb + off);
        if (has_mean) am[t] = *(const s16x8*)(mb + off);
    }

    // ---- layer 1: h = relu(mean@Wl^T + x@Wr^T + bl)  -> mb (bf16 [16][128]) ----
    for (int c = 0; c < 8; ++c) {
        f32x4 acc = {0.f, 0.f, 0.f, 0.f};
        int brow = c * 16 + arow;
#pragma unroll
        for (int t = 0; t < 4; ++t) {
            int boff = brow * 256 + (((t * 64) + acol) ^ ((brow & 7) << 4));
            s16x8 br = *(const s16x8*)(smem + LOFF_WR + boff);
            acc = __builtin_amdgcn_mfma_f32_16x16x32_bf16(ax[t], br, acc, 0, 0, 0);
        }
        if (has_mean) {
#pragma unroll
            for (int t = 0; t < 4; ++t) {
                int boff = brow * 256 + (((t * 64) + acol) ^ ((brow & 7) << 4));
                s16x8 blf = *(const s16x8*)(smem + LOFF_WL + boff);
                acc = __builtin_amdgcn_mfma_f32_16x16x32_bf16(am[t], blf, acc, 0, 0, 0);
            }
        }
        float bias = *(const float*)(smem + LOFF_BL + (c * 16 + arow) * 4);
#pragma unroll
        for (int r = 0; r < 4; ++r) {
            int row = agrp * 4 + r;
            float v = fmaxf(acc[r] + bias, 0.f);
            *(ushort*)(mb + row * 256 + ((2 * (c * 16 + arow)) ^ ((row & 7) << 4))) = f2bf(v);
        }
    }

    // ---- layer 2: h1@W1^T + b1 -> xb (bf16 [16][64], 256B row stride) ----
    s16x8 ah[4];
#pragma unroll
    for (int t = 0; t < 4; ++t) {
        int off = arow * 256 + (((t * 64) + acol) ^ ((arow & 7) << 4));
        ah[t] = *(const s16x8*)(mb + off);
    }
    for (int c = 0; c < 4; ++c) {
        f32x4 acc = {0.f, 0.f, 0.f, 0.f};
        int brow = c * 16 + arow;
#pragma unroll
        for (int t = 0; t < 4; ++t) {
            int boff = brow * 256 + (((t * 64) + acol) ^ ((brow & 7) << 4));
            s16x8 bw = *(const s16x8*)(smem + LOFF_W1 + boff);
            acc = __builtin_amdgcn_mfma_f32_16x16x32_bf16(ah[t], bw, acc, 0, 0, 0);
        }
        float bias = *(const float*)(smem + LOFF_B1 + (c * 16 + arow) * 4);
#pragma unroll
        for (int r = 0; r < 4; ++r) {
            int row = agrp * 4 + r;
            float v = fmaxf(acc[r] + bias, 0.f);
            *(ushort*)(xb + row * 256 + ((2 * (c * 16 + arow)) ^ ((row & 7) << 4))) = f2bf(v);
        }
    }

    // ---- layer 3: h2@W2^T + b2 -> mb (bf16 [16][32]) ----
    s16x8 a3[2];
#pragma unroll
    for (int t = 0; t < 2; ++t) {
        int off = arow * 256 + (((t * 64) + acol) ^ ((arow & 7) << 4));
        a3[t] = *(const s16x8*)(xb + off);
    }
    for (int c = 0; c < 2; ++c) {
        f32x4 acc = {0.f, 0.f, 0.f, 0.f};
        int brow = c * 16 + arow;
#pragma unroll
        for (int t = 0; t < 2; ++t) {
            int boff = brow * 128 + (((t * 64) + acol) ^ ((brow & 7) << 4));
            s16x8 bw = *(const s16x8*)(smem + LOFF_W2 + boff);
            acc = __builtin_amdgcn_mfma_f32_16x16x32_bf16(a3[t], bw, acc, 0, 0, 0);
        }
        float bias = *(const float*)(smem + LOFF_B2 + (c * 16 + arow) * 4);
#pragma unroll
        for (int r = 0; r < 4; ++r) {
            int row = agrp * 4 + r;
            float v = fmaxf(acc[r] + bias, 0.f);
            *(ushort*)(mb + row * 256 + ((2 * (c * 16 + arow)) ^ ((row & 7) << 4))) = f2bf(v);
        }
    }

    // ---- layer 4 + log_softmax (lanes 0..15, one edge each) ----
    if (lane < 16) {
        int i = lane;
        float l0 = *(const float*)(smem + LOFF_B3);
        float l1 = *(const float*)(smem + LOFF_B3 + 4);
#pragma unroll
        for (int cch = 0; cch < 4; ++cch) {
            s16x8 h = *(const s16x8*)(mb + i * 256 + ((cch * 16) ^ ((i & 7) << 4)));
#pragma unroll
            for (int j = 0; j < 8; ++j) {
                float f = bf2f((ushort)h[j]);
                int k = cch * 8 + j;
                l0 += f * *(const float*)(smem + LOFF_W3 + k * 4);
                l1 += f * *(const float*)(smem + LOFF_W3 + (32 + k) * 4);
            }
        }
        float m = fmaxf(l0, l1);
        float lse = m + __logf(__expf(l0 - m) + __expf(l1 - m));
        float2 p = { l0 - lse, l1 - lse };
        *(float2*)(out + (size_t)(eb + i) * 2) = p;
    }
}

extern "C" void kernel_launch(void* const* d_in, const int* in_sizes, int n_in,
                              void* d_out, int out_size, void* d_ws, size_t ws_size,
                              hipStream_t stream) {
    const float* rna  = (const float*)d_in[0];
    const float* prot = (const float*)d_in[1];
    const int*   ei   = (const int*)d_in[2];
    const float* Wl   = (const float*)d_in[3];
    const float* bl   = (const float*)d_in[4];
    const float* Wr   = (const float*)d_in[5];
    const float* W1   = (const float*)d_in[6];
    const float* b1   = (const float*)d_in[7];
    const float* W2   = (const float*)d_in[8];
    const float* b2   = (const float*)d_in[9];
    const float* W3   = (const float*)d_in[10];
    const float* b3   = (const float*)d_in[11];
    float* out = (float*)d_out;

    char* ws = (char*)d_ws;
    float*  agg  = (float*)(ws);                    // 51,200,000 B
    float*  cnt  = (float*)(ws + 51200000);         //    400,000 B
    ushort* nfbf = (ushort*)(ws + 51600000);        // 25,600,000 B
    ushort* Wbf  = (ushort*)(ws + 77200000);        //     86,016 B

    hipMemsetAsync(agg, 0, 51600000, stream);       // agg + cnt
    k_convert_weights<<<168, 256, 0, stream>>>(Wl, Wr, W1, W2, Wbf);
    k_convert_nfea<<<12500, 256, 0, stream>>>(rna, prot, nfbf);
    k_scatter<<<100000, 256, 0, stream>>>(ei, nfbf, agg, cnt);
    hipFuncSetAttribute((const void*)k_mlp, hipFuncAttributeMaxDynamicSharedMemorySize, LDS_TOTAL);
    k_mlp<<<6250, 512, LDS_TOTAL, stream>>>(ei, nfbf, agg, cnt, Wbf, bl, b1, b2, W3, b3, out);
    k_labels<<<782, 256, 0, stream>>>(out);
}

// Round 2
// 640.652 us; speedup vs baseline: 2.8641x; 2.8641x over previous
//
#include <hip/hip_runtime.h>
#include <hip/hip_bf16.h>

#define N_NODE  100000
#define N_EDGE  800000
#define FEATD   128

typedef float  f32x4 __attribute__((ext_vector_type(4)));
typedef short  s16x8 __attribute__((ext_vector_type(8)));

static __device__ __forceinline__ float bf2f(ushort h) {
    union { uint u; float f; } v; v.u = ((uint)h) << 16; return v.f;
}
static __device__ __forceinline__ ushort f2bf(float f) {
    union { float f; uint u; } v; v.f = f;
    uint u = v.u;
    u = u + 0x7FFFu + ((u >> 16) & 1u);   // RNE
    return (ushort)(u >> 16);
}

// ---------------- K1: weights f32 -> bf16 (packed into ws) ----------------
// Layout in Wbf (shorts): Wl[16384] Wr[16384] W1[8192] W2[2048]  (total 43008)
__global__ void k_convert_weights(const float* __restrict__ Wl, const float* __restrict__ Wr,
                                  const float* __restrict__ W1, const float* __restrict__ W2,
                                  ushort* __restrict__ Wbf) {
    int i = blockIdx.x * 256 + threadIdx.x;
    if (i < 16384)       Wbf[i] = f2bf(Wl[i]);
    else if (i < 32768)  Wbf[i] = f2bf(Wr[i - 16384]);
    else if (i < 40960)  Wbf[i] = f2bf(W1[i - 32768]);
    else if (i < 43008)  Wbf[i] = f2bf(W2[i - 40960]);
}

// ---------------- K2: n_fea (concat rna|prot) f32 -> bf16 ----------------
__global__ void k_convert_nfea(const float* __restrict__ rna, const float* __restrict__ prot,
                               ushort* __restrict__ nfbf) {
    int i = (blockIdx.x * 256 + threadIdx.x) * 4;
    if (i >= N_NODE * FEATD) return;
    const float* src = (i < 50000 * FEATD) ? (rna + i) : (prot + (i - 50000 * FEATD));
    float4 v = *(const float4*)src;
    ushort4 o;
    o.x = f2bf(v.x); o.y = f2bf(v.y); o.z = f2bf(v.z); o.w = f2bf(v.w);
    *(ushort4*)(nfbf + i) = o;
}

// ---------------- K3a: materialize message rows x[s] for s < 100000 (bf16) ----
__global__ void k_xlow(const int* __restrict__ ei, const ushort* __restrict__ nfbf,
                       ushort* __restrict__ xlow) {
    int t = blockIdx.x * 256 + threadIdx.x;
    int s = t >> 6, lane = t & 63;
    if (s >= N_NODE) return;
    int a = ei[s], b = ei[N_EDGE + s];
    uint ua = *(const uint*)(nfbf + (size_t)a * FEATD + lane * 2);
    uint ub = *(const uint*)(nfbf + (size_t)b * FEATD + lane * 2);
    float p0 = bf2f((ushort)(ua & 0xFFFF)) * bf2f((ushort)(ub & 0xFFFF));
    float p1 = bf2f((ushort)(ua >> 16))    * bf2f((ushort)(ub >> 16));
    *(uint*)(xlow + (size_t)s * FEATD + lane * 2) = (uint)f2bf(p0) | ((uint)f2bf(p1) << 16);
}

// ---------------- K3b: histogram of dst ----------------
__global__ void k_hist(const int* __restrict__ ei, int* __restrict__ cnt_i) {
    int e = blockIdx.x * 256 + threadIdx.x;
    if (e >= N_EDGE) return;
    atomicAdd(&cnt_i[ei[N_EDGE + e]], 1);
}

// ---------------- K3c: per-block sums of cnt_i ----------------
__global__ void k_blocksum(const int* __restrict__ cnt_i, int* __restrict__ bsum) {
    __shared__ int sh[256];
    int i = blockIdx.x * 256 + threadIdx.x;
    sh[threadIdx.x] = (i < N_NODE) ? cnt_i[i] : 0;
    __syncthreads();
    for (int o = 128; o > 0; o >>= 1) {
        if (threadIdx.x < o) sh[threadIdx.x] += sh[threadIdx.x + o];
        __syncthreads();
    }
    if (threadIdx.x == 0) bsum[blockIdx.x] = sh[0];
}

// ---------------- K3d: serial exclusive scan of 391 block sums ----------------
__global__ void k_scanbase(const int* __restrict__ bsum, int* __restrict__ bbase) {
    if (threadIdx.x == 0 && blockIdx.x == 0) {
        int acc = 0;
        for (int i = 0; i < 391; ++i) { bbase[i] = acc; acc += bsum[i]; }
    }
}

// ---------------- K3e: local exclusive scan + base -> offs, wptr ----------------
__global__ void k_scanlocal(const int* __restrict__ cnt_i, const int* __restrict__ bbase,
                            int* __restrict__ offs, int* __restrict__ wptr) {
    __shared__ int sh[256];
    int i = blockIdx.x * 256 + threadIdx.x;
    int v = (i < N_NODE) ? cnt_i[i] : 0;
    sh[threadIdx.x] = v;
    __syncthreads();
    for (int o = 1; o < 256; o <<= 1) {
        int t = (threadIdx.x >= o) ? sh[threadIdx.x - o] : 0;
        __syncthreads();
        sh[threadIdx.x] += t;
        __syncthreads();
    }
    if (i < N_NODE) {
        int excl = sh[threadIdx.x] - v + bbase[blockIdx.x];
        offs[i] = excl;
        wptr[i] = excl;
    }
}

// ---------------- K3f: fill CSR edge list (stores src id directly) ----------------
__global__ void k_fill(const int* __restrict__ ei, int* __restrict__ wptr,
                       int* __restrict__ elist) {
    int e = blockIdx.x * 256 + threadIdx.x;
    if (e >= N_EDGE) return;
    int d = ei[N_EDGE + e];
    int s = ei[e];
    int pos = atomicAdd(&wptr[d], 1);
    elist[pos] = s;
}

// ---------------- K3g: gather-side aggregation -> mean rows (bf16) ----------------
__global__ void k_agg(const int* __restrict__ cnt_i, const int* __restrict__ offs,
                      const int* __restrict__ elist, const ushort* __restrict__ xlow,
                      ushort* __restrict__ meanbf) {
    int t = blockIdx.x * 256 + threadIdx.x;
    int d = t >> 6, lane = t & 63;
    if (d >= N_NODE) return;
    int c = cnt_i[d];
    int base = offs[d];
    float a0 = 0.f, a1 = 0.f;
    for (int k = 0; k < c; ++k) {
        int s = elist[base + k];
        uint u = *(const uint*)(xlow + (size_t)s * FEATD + lane * 2);
        a0 += bf2f((ushort)(u & 0xFFFF));
        a1 += bf2f((ushort)(u >> 16));
    }
    float sc = 1.0f / fmaxf((float)c, 1.0f);
    *(uint*)(meanbf + (size_t)d * FEATD + lane * 2) =
        (uint)f2bf(a0 * sc) | ((uint)f2bf(a1 * sc) << 16);
}

// ---------------- K5: labels ----------------
__global__ void k_labels(float* __restrict__ out) {
    int base = (blockIdx.x * 256 + threadIdx.x) * 4;
    if (base >= N_EDGE) return;
    float val = (base < N_EDGE / 2) ? 1.0f : 0.0f;   // 400000 % 4 == 0: no straddle
    float4 v = { val, val, val, val };
    *(float4*)(out + 2 * (size_t)N_EDGE + base) = v;
}

// ---------------- K4: fused gather + 4-layer MLP + log_softmax ----------------
// LDS layout (bytes), all weight/buf rows XOR-swizzled: byte ^= (row&7)<<4
#define LOFF_WL   0
#define LOFF_WR   32768
#define LOFF_W1   65536
#define LOFF_W2   81920      /* 32 rows x 128B */
#define LOFF_BL   86016
#define LOFF_B1   86528
#define LOFF_B2   86784
#define LOFF_W3   86912      /* 64 f32: W3[2][32] */
#define LOFF_B3   87168
#define LOFF_XBUF 87184      /* 8 waves x 4096B: [16 rows][256B] */
#define LOFF_MBUF (87184 + 8 * 4096)
#define LDS_TOTAL (LOFF_MBUF + 8 * 4096)   /* 152720 */

__global__ __launch_bounds__(512) void k_mlp(
        const int* __restrict__ ei, const ushort* __restrict__ nfbf,
        const ushort* __restrict__ meanbf,
        const ushort* __restrict__ Wbf,
        const float* __restrict__ bl, const float* __restrict__ b1,
        const float* __restrict__ b2, const float* __restrict__ W3,
        const float* __restrict__ b3, float* __restrict__ out)
{
    extern __shared__ char smem[];
    const int tid = threadIdx.x;

    // ---- stage weights (cooperative) ----
    {
        const uint4* src = (const uint4*)Wbf;   // 16B chunks: Wl 2048 | Wr 2048 | W1 1024 | W2 256
        for (int c = tid; c < 2048; c += 512) {
            int row = c >> 4, colb = (c & 15) << 4;
            *(uint4*)(smem + LOFF_WL + row * 256 + (colb ^ ((row & 7) << 4))) = src[c];
        }
        for (int c = tid; c < 2048; c += 512) {
            int row = c >> 4, colb = (c & 15) << 4;
            *(uint4*)(smem + LOFF_WR + row * 256 + (colb ^ ((row & 7) << 4))) = src[2048 + c];
        }
        for (int c = tid; c < 1024; c += 512) {
            int row = c >> 4, colb = (c & 15) << 4;
            *(uint4*)(smem + LOFF_W1 + row * 256 + (colb ^ ((row & 7) << 4))) = src[4096 + c];
        }
        for (int c = tid; c < 256; c += 512) {
            int row = c >> 3, colb = (c & 7) << 4;
            *(uint4*)(smem + LOFF_W2 + row * 128 + (colb ^ ((row & 7) << 4))) = src[5120 + c];
        }
        if (tid < 128)      *(float*)(smem + LOFF_BL + tid * 4) = bl[tid];
        else if (tid < 192) *(float*)(smem + LOFF_B1 + (tid - 128) * 4) = b1[tid - 128];
        else if (tid < 224) *(float*)(smem + LOFF_B2 + (tid - 192) * 4) = b2[tid - 192];
        else if (tid < 288) *(float*)(smem + LOFF_W3 + (tid - 224) * 4) = W3[tid - 224];
        else if (tid < 290) *(float*)(smem + LOFF_B3 + (tid - 288) * 4) = b3[tid - 288];
    }
    __syncthreads();

    const int w = tid >> 6, lane = tid & 63;
    const int eb = blockIdx.x * 128 + w * 16;
    char* xb = smem + LOFF_XBUF + w * 4096;
    char* mb = smem + LOFF_MBUF + w * 4096;
    const bool has_mean = (eb < N_NODE);   // tiles are 16-aligned; 100000 % 16 == 0

    // ---- gather: x rows (bf16) and mean rows into LDS ----
#pragma unroll
    for (int i = 0; i < 16; ++i) {
        int e = eb + i;
        int s = ei[e], d = ei[N_EDGE + e];
        uint ua = *(const uint*)(nfbf + (size_t)s * FEATD + lane * 2);
        uint ub = *(const uint*)(nfbf + (size_t)d * FEATD + lane * 2);
        float p0 = bf2f((ushort)(ua & 0xFFFF)) * bf2f((ushort)(ub & 0xFFFF));
        float p1 = bf2f((ushort)(ua >> 16))    * bf2f((ushort)(ub >> 16));
        uint pk = (uint)f2bf(p0) | ((uint)f2bf(p1) << 16);
        *(uint*)(xb + i * 256 + ((lane * 4) ^ ((i & 7) << 4))) = pk;
        if (has_mean) {
            uint mk = *(const uint*)(meanbf + (size_t)e * FEATD + lane * 2);
            *(uint*)(mb + i * 256 + ((lane * 4) ^ ((i & 7) << 4))) = mk;
        }
    }

    const int arow = lane & 15, agrp = lane >> 4;
    const int acol = agrp * 16;   // byte offset of this lane's 16B chunk within a 64B k-step

    // ---- A fragments for layer 1 ----
    s16x8 ax[4], am[4] = {};
#pragma unroll
    for (int t = 0; t < 4; ++t) {
        int off = arow * 256 + (((t * 64) + acol) ^ ((arow & 7) << 4));
        ax[t] = *(const s16x8*)(xb + off);
        if (has_mean) am[t] = *(const s16x8*)(mb + off);
    }

    // ---- layer 1: h = relu(mean@Wl^T + x@Wr^T + bl)  -> mb (bf16 [16][128]) ----
    for (int c = 0; c < 8; ++c) {
        f32x4 acc = {0.f, 0.f, 0.f, 0.f};
        int brow = c * 16 + arow;
#pragma unroll
        for (int t = 0; t < 4; ++t) {
            int boff = brow * 256 + (((t * 64) + acol) ^ ((brow & 7) << 4));
            s16x8 br = *(const s16x8*)(smem + LOFF_WR + boff);
            acc = __builtin_amdgcn_mfma_f32_16x16x32_bf16(ax[t], br, acc, 0, 0, 0);
        }
        if (has_mean) {
#pragma unroll
            for (int t = 0; t < 4; ++t) {
                int boff = brow * 256 + (((t * 64) + acol) ^ ((brow & 7) << 4));
                s16x8 blf = *(const s16x8*)(smem + LOFF_WL + boff);
                acc = __builtin_amdgcn_mfma_f32_16x16x32_bf16(am[t], blf, acc, 0, 0, 0);
            }
        }
        float bias = *(const float*)(smem + LOFF_BL + (c * 16 + arow) * 4);
#pragma unroll
        for (int r = 0; r < 4; ++r) {
            int row = agrp * 4 + r;
            float v = fmaxf(acc[r] + bias, 0.f);
            *(ushort*)(mb + row * 256 + ((2 * (c * 16 + arow)) ^ ((row & 7) << 4))) = f2bf(v);
        }
    }

    // ---- layer 2: h1@W1^T + b1 -> xb (bf16 [16][64], 256B row stride) ----
    s16x8 ah[4];
#pragma unroll
    for (int t = 0; t < 4; ++t) {
        int off = arow * 256 + (((t * 64) + acol) ^ ((arow & 7) << 4));
        ah[t] = *(const s16x8*)(mb + off);
    }
    for (int c = 0; c < 4; ++c) {
        f32x4 acc = {0.f, 0.f, 0.f, 0.f};
        int brow = c * 16 + arow;
#pragma unroll
        for (int t = 0; t < 4; ++t) {
            int boff = brow * 256 + (((t * 64) + acol) ^ ((brow & 7) << 4));
            s16x8 bw = *(const s16x8*)(smem + LOFF_W1 + boff);
            acc = __builtin_amdgcn_mfma_f32_16x16x32_bf16(ah[t], bw, acc, 0, 0, 0);
        }
        float bias = *(const float*)(smem + LOFF_B1 + (c * 16 + arow) * 4);
#pragma unroll
        for (int r = 0; r < 4; ++r) {
            int row = agrp * 4 + r;
            float v = fmaxf(acc[r] + bias, 0.f);
            *(ushort*)(xb + row * 256 + ((2 * (c * 16 + arow)) ^ ((row & 7) << 4))) = f2bf(v);
        }
    }

    // ---- layer 3: h2@W2^T + b2 -> mb (bf16 [16][32]) ----
    s16x8 a3[2];
#pragma unroll
    for (int t = 0; t < 2; ++t) {
        int off = arow * 256 + (((t * 64) + acol) ^ ((arow & 7) << 4));
        a3[t] = *(const s16x8*)(xb + off);
    }
    for (int c = 0; c < 2; ++c) {
        f32x4 acc = {0.f, 0.f, 0.f, 0.f};
        int brow = c * 16 + arow;
#pragma unroll
        for (int t = 0; t < 2; ++t) {
            int boff = brow * 128 + (((t * 64) + acol) ^ ((brow & 7) << 4));
            s16x8 bw = *(const s16x8*)(smem + LOFF_W2 + boff);
            acc = __builtin_amdgcn_mfma_f32_16x16x32_bf16(a3[t], bw, acc, 0, 0, 0);
        }
        float bias = *(const float*)(smem + LOFF_B2 + (c * 16 + arow) * 4);
#pragma unroll
        for (int r = 0; r < 4; ++r) {
            int row = agrp * 4 + r;
            float v = fmaxf(acc[r] + bias, 0.f);
            *(ushort*)(mb + row * 256 + ((2 * (c * 16 + arow)) ^ ((row & 7) << 4))) = f2bf(v);
        }
    }

    // ---- layer 4 + log_softmax (lanes 0..15, one edge each) ----
    if (lane < 16) {
        int i = lane;
        float l0 = *(const float*)(smem + LOFF_B3);
        float l1 = *(const float*)(smem + LOFF_B3 + 4);
#pragma unroll
        for (int cch = 0; cch < 4; ++cch) {
            s16x8 h = *(const s16x8*)(mb + i * 256 + ((cch * 16) ^ ((i & 7) << 4)));
#pragma unroll
            for (int j = 0; j < 8; ++j) {
                float f = bf2f((ushort)h[j]);
                int k = cch * 8 + j;
                l0 += f * *(const float*)(smem + LOFF_W3 + k * 4);
                l1 += f * *(const float*)(smem + LOFF_W3 + (32 + k) * 4);
            }
        }
        float m = fmaxf(l0, l1);
        float lse = m + __logf(__expf(l0 - m) + __expf(l1 - m));
        float2 p = { l0 - lse, l1 - lse };
        *(float2*)(out + (size_t)(eb + i) * 2) = p;
    }
}

extern "C" void kernel_launch(void* const* d_in, const int* in_sizes, int n_in,
                              void* d_out, int out_size, void* d_ws, size_t ws_size,
                              hipStream_t stream) {
    const float* rna  = (const float*)d_in[0];
    const float* prot = (const float*)d_in[1];
    const int*   ei   = (const int*)d_in[2];
    const float* Wl   = (const float*)d_in[3];
    const float* bl   = (const float*)d_in[4];
    const float* Wr   = (const float*)d_in[5];
    const float* W1   = (const float*)d_in[6];
    const float* b1   = (const float*)d_in[7];
    const float* W2   = (const float*)d_in[8];
    const float* b2   = (const float*)d_in[9];
    const float* W3   = (const float*)d_in[10];
    const float* b3   = (const float*)d_in[11];
    float* out = (float*)d_out;

    char* ws = (char*)d_ws;
    ushort* nfbf   = (ushort*)(ws);                  // 25,600,000 B
    ushort* xlow   = (ushort*)(ws + 25600000);       // 25,600,000 B
    ushort* meanbf = (ushort*)(ws + 51200000);       // 25,600,000 B
    ushort* Wbf    = (ushort*)(ws + 76800000);       //     86,016 B
    int*    cnt_i  = (int*)   (ws + 76886016);       //    400,000 B
    int*    offs   = (int*)   (ws + 77286016);       //    400,000 B
    int*    wptr   = (int*)   (ws + 77686016);       //    400,000 B
    int*    elist  = (int*)   (ws + 78086016);       //  3,200,000 B
    int*    bsum   = (int*)   (ws + 81286016);       //      1,564 B
    int*    bbase  = (int*)   (ws + 81288064);       //      1,564 B  (total ~81.3 MB)

    hipMemsetAsync(cnt_i, 0, 400000, stream);
    k_convert_weights<<<168, 256, 0, stream>>>(Wl, Wr, W1, W2, Wbf);
    k_convert_nfea<<<12500, 256, 0, stream>>>(rna, prot, nfbf);
    k_xlow<<<25000, 256, 0, stream>>>(ei, nfbf, xlow);
    k_hist<<<3125, 256, 0, stream>>>(ei, cnt_i);
    k_blocksum<<<391, 256, 0, stream>>>(cnt_i, bsum);
    k_scanbase<<<1, 64, 0, stream>>>(bsum, bbase);
    k_scanlocal<<<391, 256, 0, stream>>>(cnt_i, bbase, offs, wptr);
    k_fill<<<3125, 256, 0, stream>>>(ei, wptr, elist);
    k_agg<<<25000, 256, 0, stream>>>(cnt_i, offs, elist, xlow, meanbf);
    hipFuncSetAttribute((const void*)k_mlp, hipFuncAttributeMaxDynamicSharedMemorySize, LDS_TOTAL);
    k_mlp<<<6250, 512, LDS_TOTAL, stream>>>(ei, nfbf, meanbf, Wbf, bl, b1, b2, W3, b3, out);
    k_labels<<<782, 256, 0, stream>>>(out);
}

// Round 3
// 326.935 us; speedup vs baseline: 5.6125x; 1.9596x over previous
//
#include <hip/hip_runtime.h>
#include <hip/hip_bf16.h>

#define N_NODE  100000
#define N_EDGE  800000
#define FEATD   128
#define NTILES  3125          /* 800000 / 256 edges per block-tile */

typedef float  f32x4 __attribute__((ext_vector_type(4)));
typedef short  s16x8 __attribute__((ext_vector_type(8)));

static __device__ __forceinline__ float bf2f(ushort h) {
    union { uint u; float f; } v; v.u = ((uint)h) << 16; return v.f;
}
static __device__ __forceinline__ ushort f2bf(float f) {
    union { float f; uint u; } v; v.f = f;
    uint u = v.u;
    u = u + 0x7FFFu + ((u >> 16) & 1u);   // RNE
    return (ushort)(u >> 16);
}

// ---------------- K2: n_fea (concat rna|prot) f32 -> bf16 ----------------
__global__ void k_convert_nfea(const float* __restrict__ rna, const float* __restrict__ prot,
                               ushort* __restrict__ nfbf) {
    int i = (blockIdx.x * 256 + threadIdx.x) * 4;
    if (i >= N_NODE * FEATD) return;
    const float* src = (i < 50000 * FEATD) ? (rna + i) : (prot + (i - 50000 * FEATD));
    float4 v = *(const float4*)src;
    ushort4 o;
    o.x = f2bf(v.x); o.y = f2bf(v.y); o.z = f2bf(v.z); o.w = f2bf(v.w);
    *(ushort4*)(nfbf + i) = o;
}

// ---------------- K3a: materialize message rows x[s] for s < 100000 (bf16) ----
__global__ void k_xlow(const int* __restrict__ ei, const ushort* __restrict__ nfbf,
                       ushort* __restrict__ xlow) {
    int t = blockIdx.x * 256 + threadIdx.x;
    int s = t >> 6, lane = t & 63;
    if (s >= N_NODE) return;
    int a = ei[s], b = ei[N_EDGE + s];
    uint ua = *(const uint*)(nfbf + (size_t)a * FEATD + lane * 2);
    uint ub = *(const uint*)(nfbf + (size_t)b * FEATD + lane * 2);
    float p0 = bf2f((ushort)(ua & 0xFFFF)) * bf2f((ushort)(ub & 0xFFFF));
    float p1 = bf2f((ushort)(ua >> 16))    * bf2f((ushort)(ub >> 16));
    *(uint*)(xlow + (size_t)s * FEATD + lane * 2) = (uint)f2bf(p0) | ((uint)f2bf(p1) << 16);
}

// ---------------- K3b: histogram of dst ----------------
__global__ void k_hist(const int* __restrict__ ei, int* __restrict__ cnt_i) {
    int e = blockIdx.x * 256 + threadIdx.x;
    if (e >= N_EDGE) return;
    atomicAdd(&cnt_i[ei[N_EDGE + e]], 1);
}

// ---------------- K3c: per-block sums of cnt_i ----------------
__global__ void k_blocksum(const int* __restrict__ cnt_i, int* __restrict__ bsum) {
    __shared__ int sh[256];
    int i = blockIdx.x * 256 + threadIdx.x;
    sh[threadIdx.x] = (i < N_NODE) ? cnt_i[i] : 0;
    __syncthreads();
    for (int o = 128; o > 0; o >>= 1) {
        if (threadIdx.x < o) sh[threadIdx.x] += sh[threadIdx.x + o];
        __syncthreads();
    }
    if (threadIdx.x == 0) bsum[blockIdx.x] = sh[0];
}

// ---------------- K3d: serial exclusive scan of 391 block sums ----------------
__global__ void k_scanbase(const int* __restrict__ bsum, int* __restrict__ bbase) {
    if (threadIdx.x == 0 && blockIdx.x == 0) {
        int acc = 0;
        for (int i = 0; i < 391; ++i) { bbase[i] = acc; acc += bsum[i]; }
    }
}

// ---------------- K3e: local exclusive scan + base -> offs, wptr ----------------
__global__ void k_scanlocal(const int* __restrict__ cnt_i, const int* __restrict__ bbase,
                            int* __restrict__ offs, int* __restrict__ wptr) {
    __shared__ int sh[256];
    int i = blockIdx.x * 256 + threadIdx.x;
    int v = (i < N_NODE) ? cnt_i[i] : 0;
    sh[threadIdx.x] = v;
    __syncthreads();
    for (int o = 1; o < 256; o <<= 1) {
        int t = (threadIdx.x >= o) ? sh[threadIdx.x - o] : 0;
        __syncthreads();
        sh[threadIdx.x] += t;
        __syncthreads();
    }
    if (i < N_NODE) {
        int excl = sh[threadIdx.x] - v + bbase[blockIdx.x];
        offs[i] = excl;
        wptr[i] = excl;
    }
}

// ---------------- K3f: fill CSR edge list (stores src id directly) ----------------
__global__ void k_fill(const int* __restrict__ ei, int* __restrict__ wptr,
                       int* __restrict__ elist) {
    int e = blockIdx.x * 256 + threadIdx.x;
    if (e >= N_EDGE) return;
    int d = ei[N_EDGE + e];
    int s = ei[e];
    int pos = atomicAdd(&wptr[d], 1);
    elist[pos] = s;
}

// ---------------- K3g: gather-side aggregation -> mean rows (bf16) ----------------
__global__ void k_agg(const int* __restrict__ cnt_i, const int* __restrict__ offs,
                      const int* __restrict__ elist, const ushort* __restrict__ xlow,
                      ushort* __restrict__ meanbf) {
    int t = blockIdx.x * 256 + threadIdx.x;
    int d = t >> 6, lane = t & 63;
    if (d >= N_NODE) return;
    int c = cnt_i[d];
    int base = offs[d];
    float a0 = 0.f, a1 = 0.f;
    for (int k = 0; k < c; ++k) {
        int s = elist[base + k];
        uint u = *(const uint*)(xlow + (size_t)s * FEATD + lane * 2);
        a0 += bf2f((ushort)(u & 0xFFFF));
        a1 += bf2f((ushort)(u >> 16));
    }
    float sc = 1.0f / fmaxf((float)c, 1.0f);
    *(uint*)(meanbf + (size_t)d * FEATD + lane * 2) =
        (uint)f2bf(a0 * sc) | ((uint)f2bf(a1 * sc) << 16);
}

// ---------------- K5: labels ----------------
__global__ void k_labels(float* __restrict__ out) {
    int base = (blockIdx.x * 256 + threadIdx.x) * 4;
    if (base >= N_EDGE) return;
    float val = (base < N_EDGE / 2) ? 1.0f : 0.0f;   // 400000 % 4 == 0: no straddle
    float4 v = { val, val, val, val };
    *(float4*)(out + 2 * (size_t)N_EDGE + base) = v;
}

// ---------------- K4: persistent fused gather + 4-layer MLP + log_softmax ----
// LDS (bytes), weights XOR-swizzled: byte ^= (row&7)<<4 within 16B granules
#define LOFF_WL   0           /* 128 rows x 256B bf16 */
#define LOFF_WR   32768
#define LOFF_W1   65536       /* 64 rows x 256B */
#define LOFF_W2   81920       /* 32 rows x 128B */
#define LOFF_BL   86016
#define LOFF_B1   86528
#define LOFF_B2   86784
#define LOFF_W3   86912       /* 64 f32: W3[2][32] */
#define LOFF_B3   87168
#define LOFF_ABUF 87184       /* 16 waves x 4096B: [16 rows][256B] transpose buf */
#define LDS_TOTAL (LOFF_ABUF + 16 * 4096)   /* 152720 */

__global__ __launch_bounds__(1024, 4) void k_mlp(
        const int* __restrict__ ei, const ushort* __restrict__ nfbf,
        const ushort* __restrict__ xlow, const ushort* __restrict__ meanbf,
        const float* __restrict__ Wl, const float* __restrict__ Wr,
        const float* __restrict__ W1, const float* __restrict__ W2,
        const float* __restrict__ bl, const float* __restrict__ b1,
        const float* __restrict__ b2, const float* __restrict__ W3,
        const float* __restrict__ b3, float* __restrict__ out)
{
    extern __shared__ char smem[];
    const int tid = threadIdx.x;

    // ---- stage weights once per block (f32 -> bf16 -> swizzled LDS) ----
    for (int i = tid; i < 16384; i += 1024) {
        int row = i >> 7, col = i & 127;
        int sw = (row & 7) << 4;
        *(ushort*)(smem + LOFF_WL + row * 256 + ((2 * col) ^ sw)) = f2bf(Wl[i]);
        *(ushort*)(smem + LOFF_WR + row * 256 + ((2 * col) ^ sw)) = f2bf(Wr[i]);
    }
    for (int i = tid; i < 8192; i += 1024) {
        int row = i >> 7, col = i & 127;
        *(ushort*)(smem + LOFF_W1 + row * 256 + ((2 * col) ^ ((row & 7) << 4))) = f2bf(W1[i]);
    }
    for (int i = tid; i < 2048; i += 1024) {
        int row = i >> 6, col = i & 63;
        *(ushort*)(smem + LOFF_W2 + row * 128 + ((2 * col) ^ ((row & 7) << 4))) = f2bf(W2[i]);
    }
    if (tid < 128)      *(float*)(smem + LOFF_BL + tid * 4) = bl[tid];
    else if (tid < 192) *(float*)(smem + LOFF_B1 + (tid - 128) * 4) = b1[tid - 128];
    else if (tid < 224) *(float*)(smem + LOFF_B2 + (tid - 192) * 4) = b2[tid - 192];
    else if (tid < 288) *(float*)(smem + LOFF_W3 + (tid - 224) * 4) = W3[tid - 224];
    else if (tid < 290) *(float*)(smem + LOFF_B3 + (tid - 288) * 4) = b3[tid - 288];
    __syncthreads();

    const int w = tid >> 6, lane = tid & 63;
    const int arow = lane & 15, agrp = lane >> 4;
    char* ab = smem + LOFF_ABUF + w * 4096;
    const float* W3s = (const float*)(smem + LOFF_W3);
    const float* B3s = (const float*)(smem + LOFF_B3);

    for (int tile = blockIdx.x; tile < NTILES; tile += gridDim.x) {
        const int eb = tile * 256 + w * 16;          // this wave's 16 edges
        const bool low = (eb < N_NODE);              // 16-aligned boundary: exact

        // ---- build layer-1 A fragments directly in registers ----
        s16x8 ax[4], am[4];
        if (low) {
            const ushort* xr = xlow   + (size_t)(eb + arow) * FEATD + agrp * 8;
            const ushort* mr = meanbf + (size_t)(eb + arow) * FEATD + agrp * 8;
#pragma unroll
            for (int t = 0; t < 4; ++t) {
                ax[t] = *(const s16x8*)(xr + t * 32);
                am[t] = *(const s16x8*)(mr + t * 32);
            }
        } else {
            int e = eb + arow;
            int s = ei[e], d = ei[N_EDGE + e];
            const ushort* sr = nfbf + (size_t)s * FEATD + agrp * 8;
            const ushort* dr = nfbf + (size_t)d * FEATD + agrp * 8;
            s16x8 av[4], bv[4];
#pragma unroll
            for (int t = 0; t < 4; ++t) {
                av[t] = *(const s16x8*)(sr + t * 32);
                bv[t] = *(const s16x8*)(dr + t * 32);
            }
#pragma unroll
            for (int t = 0; t < 4; ++t) {
                uint* o = (uint*)&ax[t];
#pragma unroll
                for (int j = 0; j < 4; ++j) {
                    float p0 = bf2f((ushort)av[t][2 * j])     * bf2f((ushort)bv[t][2 * j]);
                    float p1 = bf2f((ushort)av[t][2 * j + 1]) * bf2f((ushort)bv[t][2 * j + 1]);
                    o[j] = (uint)f2bf(p0) | ((uint)f2bf(p1) << 16);
                }
            }
        }

        // ---- layer 1: h1 = relu(x@Wr^T + mean@Wl^T + bl) -> ab [16][256B] ----
#pragma unroll
        for (int c = 0; c < 8; ++c) {
            f32x4 acc = {0.f, 0.f, 0.f, 0.f};
            int brow = c * 16 + arow;
            int sw = (brow & 7) << 4;
#pragma unroll
            for (int t = 0; t < 4; ++t) {
                s16x8 br = *(const s16x8*)(smem + LOFF_WR + brow * 256 + ((t * 64 + agrp * 16) ^ sw));
                acc = __builtin_amdgcn_mfma_f32_16x16x32_bf16(ax[t], br, acc, 0, 0, 0);
            }
            if (low) {
#pragma unroll
                for (int t = 0; t < 4; ++t) {
                    s16x8 bw = *(const s16x8*)(smem + LOFF_WL + brow * 256 + ((t * 64 + agrp * 16) ^ sw));
                    acc = __builtin_amdgcn_mfma_f32_16x16x32_bf16(am[t], bw, acc, 0, 0, 0);
                }
            }
            float bias = *(const float*)(smem + LOFF_BL + brow * 4);
#pragma unroll
            for (int r = 0; r < 4; ++r) {
                int row = agrp * 4 + r;
                *(ushort*)(ab + row * 256 + ((2 * brow) ^ ((row & 7) << 4))) =
                    f2bf(fmaxf(acc[r] + bias, 0.f));
            }
        }

        // ---- layer 2: h2 = relu(h1@W1^T + b1) ----
        s16x8 ah[4];
#pragma unroll
        for (int t = 0; t < 4; ++t)
            ah[t] = *(const s16x8*)(ab + arow * 256 + ((t * 64 + agrp * 16) ^ ((arow & 7) << 4)));
#pragma unroll
        for (int c = 0; c < 4; ++c) {
            f32x4 acc = {0.f, 0.f, 0.f, 0.f};
            int brow = c * 16 + arow;
            int sw = (brow & 7) << 4;
#pragma unroll
            for (int t = 0; t < 4; ++t) {
                s16x8 bw = *(const s16x8*)(smem + LOFF_W1 + brow * 256 + ((t * 64 + agrp * 16) ^ sw));
                acc = __builtin_amdgcn_mfma_f32_16x16x32_bf16(ah[t], bw, acc, 0, 0, 0);
            }
            float bias = *(const float*)(smem + LOFF_B1 + brow * 4);
#pragma unroll
            for (int r = 0; r < 4; ++r) {
                int row = agrp * 4 + r;
                *(ushort*)(ab + row * 256 + ((2 * brow) ^ ((row & 7) << 4))) =
                    f2bf(fmaxf(acc[r] + bias, 0.f));
            }
        }

        // ---- layer 3: h3 = relu(h2@W2^T + b2) ----
        s16x8 a3[2];
#pragma unroll
        for (int t = 0; t < 2; ++t)
            a3[t] = *(const s16x8*)(ab + arow * 256 + ((t * 64 + agrp * 16) ^ ((arow & 7) << 4)));
#pragma unroll
        for (int c = 0; c < 2; ++c) {
            f32x4 acc = {0.f, 0.f, 0.f, 0.f};
            int brow = c * 16 + arow;
            int sw = (brow & 7) << 4;
#pragma unroll
            for (int t = 0; t < 2; ++t) {
                s16x8 bw = *(const s16x8*)(smem + LOFF_W2 + brow * 128 + ((t * 64 + agrp * 16) ^ sw));
                acc = __builtin_amdgcn_mfma_f32_16x16x32_bf16(a3[t], bw, acc, 0, 0, 0);
            }
            float bias = *(const float*)(smem + LOFF_B2 + brow * 4);
#pragma unroll
            for (int r = 0; r < 4; ++r) {
                int row = agrp * 4 + r;
                *(ushort*)(ab + row * 256 + ((2 * brow) ^ ((row & 7) << 4))) =
                    f2bf(fmaxf(acc[r] + bias, 0.f));
            }
        }

        // ---- layer 4 + log_softmax: 4 lanes per edge + shfl reduce ----
        {
            s16x8 h = *(const s16x8*)(ab + arow * 256 + ((agrp * 16) ^ ((arow & 7) << 4)));
            float l0 = 0.f, l1 = 0.f;
#pragma unroll
            for (int j = 0; j < 8; ++j) {
                float f = bf2f((ushort)h[j]);
                l0 += f * W3s[agrp * 8 + j];
                l1 += f * W3s[32 + agrp * 8 + j];
            }
            l0 += __shfl_xor(l0, 16); l0 += __shfl_xor(l0, 32);
            l1 += __shfl_xor(l1, 16); l1 += __shfl_xor(l1, 32);
            if (agrp == 0) {
                l0 += B3s[0]; l1 += B3s[1];
                float m = fmaxf(l0, l1);
                float lse = m + __logf(__expf(l0 - m) + __expf(l1 - m));
                float2 p = { l0 - lse, l1 - lse };
                *(float2*)(out + (size_t)(eb + arow) * 2) = p;
            }
        }
    }
}

extern "C" void kernel_launch(void* const* d_in, const int* in_sizes, int n_in,
                              void* d_out, int out_size, void* d_ws, size_t ws_size,
                              hipStream_t stream) {
    const float* rna  = (const float*)d_in[0];
    const float* prot = (const float*)d_in[1];
    const int*   ei   = (const int*)d_in[2];
    const float* Wl   = (const float*)d_in[3];
    const float* bl   = (const float*)d_in[4];
    const float* Wr   = (const float*)d_in[5];
    const float* W1   = (const float*)d_in[6];
    const float* b1   = (const float*)d_in[7];
    const float* W2   = (const float*)d_in[8];
    const float* b2   = (const float*)d_in[9];
    const float* W3   = (const float*)d_in[10];
    const float* b3   = (const float*)d_in[11];
    float* out = (float*)d_out;

    char* ws = (char*)d_ws;
    ushort* nfbf   = (ushort*)(ws);                  // 25,600,000 B
    ushort* xlow   = (ushort*)(ws + 25600000);       // 25,600,000 B
    ushort* meanbf = (ushort*)(ws + 51200000);       // 25,600,000 B
    int*    cnt_i  = (int*)   (ws + 76800000);       //    400,000 B
    int*    offs   = (int*)   (ws + 77200000);       //    400,000 B
    int*    wptr   = (int*)   (ws + 77600000);       //    400,000 B
    int*    elist  = (int*)   (ws + 78000000);       //  3,200,000 B
    int*    bsum   = (int*)   (ws + 81200000);       //      1,564 B
    int*    bbase  = (int*)   (ws + 81202048);       //      1,564 B

    hipMemsetAsync(cnt_i, 0, 400000, stream);
    k_convert_nfea<<<12500, 256, 0, stream>>>(rna, prot, nfbf);
    k_xlow<<<25000, 256, 0, stream>>>(ei, nfbf, xlow);
    k_hist<<<3125, 256, 0, stream>>>(ei, cnt_i);
    k_blocksum<<<391, 256, 0, stream>>>(cnt_i, bsum);
    k_scanbase<<<1, 64, 0, stream>>>(bsum, bbase);
    k_scanlocal<<<391, 256, 0, stream>>>(cnt_i, bbase, offs, wptr);
    k_fill<<<3125, 256, 0, stream>>>(ei, wptr, elist);
    k_agg<<<25000, 256, 0, stream>>>(cnt_i, offs, elist, xlow, meanbf);
    hipFuncSetAttribute((const void*)k_mlp, hipFuncAttributeMaxDynamicSharedMemorySize, LDS_TOTAL);
    k_mlp<<<512, 1024, LDS_TOTAL, stream>>>(ei, nfbf, xlow, meanbf,
                                            Wl, Wr, W1, W2, bl, b1, b2, W3, b3, out);
    k_labels<<<782, 256, 0, stream>>>(out);
}